// Round 19
// baseline (111.400 us; speedup 1.0000x reference)
//
#include <hip/hip_runtime.h>
#include <hip/hip_bf16.h>
#include <stdint.h>

typedef __bf16 bf16_t;
typedef __bf16 bf16x8 __attribute__((ext_vector_type(8)));
typedef float  f32x4  __attribute__((ext_vector_type(4)));

#define AS1 __attribute__((address_space(1)))
#define AS3 __attribute__((address_space(3)))

__device__ __forceinline__ void gload16(const bf16_t* g, char* l) {
  __builtin_amdgcn_global_load_lds((AS1 const void*)(uintptr_t)g, (AS3 void*)l, 16, 0, 0);
}
__device__ __forceinline__ int swz8(int r) { return (r & 7) ^ ((r >> 2) & 6); }

#define C2S 0.36067376022224085f   /* 0.25 * log2(e) */

// ---------------- prep: weight transposes only (x handled by gemm8 directly) ----------------
// grid 4096 = 3072 (Wqkv 1024x3072 -> [3072][1024]) + 1024 (Wout)
__global__ __launch_bounds__(256) void prep(
    const float* __restrict__ Wqkv, const float* __restrict__ Wout,
    bf16_t* __restrict__ wqkvT, bf16_t* __restrict__ woutT) {
  __shared__ float tile[32][33];
  const int bid = blockIdx.x, tid = threadIdx.x;
  const float* W; bf16_t* Wt; int N, tb;
  if (bid < 3072) { W = Wqkv; Wt = wqkvT; N = 3072; tb = bid; }
  else            { W = Wout; Wt = woutT; N = 1024; tb = bid - 3072; }
  const int kb = (tb & 31) * 32, nb = (tb >> 5) * 32;
  const int tx = tid & 31, ty = tid >> 5;
#pragma unroll
  for (int i = 0; i < 32; i += 8)
    tile[ty + i][tx] = W[(size_t)(kb + ty + i) * N + nb + tx];
  __syncthreads();
  const int r = tid >> 3;
  const int c0 = (tid & 7) * 4;
  union { bf16_t h4[4]; unsigned long long u; } pk;
#pragma unroll
  for (int j = 0; j < 4; ++j) pk.h4[j] = (bf16_t)tile[c0 + j][r];
  *reinterpret_cast<unsigned long long*>(&Wt[(size_t)(nb + r) * 1024 + kb + c0]) = pk.u;
}

// ---------------- gemm8: 128x128 tile, BK=32, 8 waves (2x4) ----------------
// A read DIRECTLY from f32 x: reg-staged (2x float4/thread), cvt->ds_write_b128
// into the same swizzled layout (dest-swizzled). B staged via gload16 as before.
// 3-buffer LDS (48KB), depth-2 prefetch. Manual vmcnt 4/1/0 guards B; the cvt's
// register use makes the compiler guard A precisely. lgkmcnt(0) drains ds_write
// before each publish barrier. Rectangular XCD swizzle (8bm x 12bn / XCD).
__global__ __launch_bounds__(512) void gemm8(
    const float* __restrict__ X, const bf16_t* __restrict__ Bt,
    const float* __restrict__ bias,
    bf16_t* __restrict__ outb, bf16_t* __restrict__ vtb,
    int N, int K, int ldo) {
  __shared__ bf16_t lA[3][4096];
  __shared__ bf16_t lB[3][4096];
  const int tid = threadIdx.x;
  const int wave = tid >> 6, lane = tid & 63;
  const int lr = lane & 15, lg = lane >> 4;
  const int ntiles = N >> 7;
  int bm, bn;
  if (ntiles == 24) {
    const int xcd = blockIdx.x & 7, l = blockIdx.x >> 3;
    bm = (xcd >> 1) * 8 + (l & 7);
    bn = (xcd & 1) * 12 + (l >> 3);
  } else {
    const int bid = (blockIdx.x & 7) * ((int)gridDim.x >> 3) + (blockIdx.x >> 3);
    bn = bid % ntiles; bm = bid / ntiles;
  }
  const int m0 = bm * 128, n0 = bn * 128;
  const int wr = wave >> 2, wc = wave & 3;
  f32x4 acc[4][2] = {};

  // ---- A: f32 reg-staging (row = tid>>2, 8 f32 cols/thread) ----
  const int arow = tid >> 2;                       // 0..127
  const int ac0 = (tid & 3) * 8;                   // f32 col offset in 32-col tile
  const float* pAx = X + (size_t)(m0 + arow) * (size_t)K + ac0;
  const int adst = arow * 64 + (((tid & 3) << 4) ^ (((arow >> 1) & 3) << 4));
  auto cvtwr = [&](int buf, const f32x4& lo, const f32x4& hi) {
    bf16x8 v;
    v[0] = (bf16_t)lo[0]; v[1] = (bf16_t)lo[1]; v[2] = (bf16_t)lo[2]; v[3] = (bf16_t)lo[3];
    v[4] = (bf16_t)hi[0]; v[5] = (bf16_t)hi[1]; v[6] = (bf16_t)hi[2]; v[7] = (bf16_t)hi[3];
    *reinterpret_cast<bf16x8*>((char*)&lA[buf][0] + adst) = v;
  };

  // ---- B: gload16 staging (pre-swizzled source), unchanged ----
  const int srow = tid >> 2;
  const int scolb = ((tid & 3) << 4) ^ (((srow >> 1) & 3) << 4);
  const bf16_t* Bsrc = Bt + (size_t)(n0 + srow) * K + (scolb >> 1);
  auto stageB = [&](int buf, int k0) {
    gload16(Bsrc + k0, (char*)&lB[buf][0] + wave * 1024);
  };

  auto ldA = [&](const char* p, int mi) {
    const int row = wr * 64 + mi * 16 + lr;
    return *reinterpret_cast<const bf16x8*>(p + row * 64 + ((lg * 16) ^ (((row >> 1) & 3) << 4)));
  };
  auto ldB = [&](const char* p, int ni) {
    const int row = wc * 32 + ni * 16 + lr;
    return *reinterpret_cast<const bf16x8*>(p + row * 64 + ((lg * 16) ^ (((row >> 1) & 3) << 4)));
  };

  const int nt = K >> 5;
  // prologue: lA[0], lA[1] written synchronously; B(0..2) gloads; A(2) regs in flight
  {
    f32x4 lo = *reinterpret_cast<const f32x4*>(pAx);
    f32x4 hi = *reinterpret_cast<const f32x4*>(pAx + 4);
    cvtwr(0, lo, hi);
    lo = *reinterpret_cast<const f32x4*>(pAx + 32);
    hi = *reinterpret_cast<const f32x4*>(pAx + 36);
    cvtwr(1, lo, hi);
  }
  stageB(0, 0);
  stageB(1, 32);
  f32x4 nlo = *reinterpret_cast<const f32x4*>(pAx + 64);
  f32x4 nhi = *reinterpret_cast<const f32x4*>(pAx + 68);
  stageB(2, 64);
  asm volatile("s_waitcnt lgkmcnt(0)" ::: "memory");   // prologue ds_writes visible

  for (int t = 0; t < nt; ++t) {
    const int cur = t % 3;
    if (t >= 1 && t + 1 < nt) {
      cvtwr((t + 1) % 3, nlo, nhi);                    // compiler waits A(t+1) here
      asm volatile("s_waitcnt lgkmcnt(0)" ::: "memory");
      if (t + 2 < nt) {
        nlo = *reinterpret_cast<const f32x4*>(pAx + (t + 2) * 32);
        nhi = *reinterpret_cast<const f32x4*>(pAx + (t + 2) * 32 + 4);
        stageB((t + 2) % 3, (t + 2) * 32);
      }
    }
    if (t + 2 < nt)      asm volatile("s_waitcnt vmcnt(4)" ::: "memory");
    else if (t + 1 < nt) asm volatile("s_waitcnt vmcnt(1)" ::: "memory");
    else                 asm volatile("s_waitcnt vmcnt(0)" ::: "memory");
    __builtin_amdgcn_s_barrier();            // publish buf[cur]
    __builtin_amdgcn_sched_barrier(0);

    const char* pA = (const char*)&lA[cur][0];
    const char* pB = (const char*)&lB[cur][0];
    bf16x8 af[4], bfv[2];
#pragma unroll
    for (int mi = 0; mi < 4; ++mi) af[mi] = ldA(pA, mi);
    bfv[0] = ldB(pB, 0); bfv[1] = ldB(pB, 1);

    __builtin_amdgcn_s_setprio(1);
#pragma unroll
    for (int mi = 0; mi < 4; ++mi)
#pragma unroll
      for (int ni = 0; ni < 2; ++ni)
        acc[mi][ni] = __builtin_amdgcn_mfma_f32_16x16x32_bf16(af[mi], bfv[ni], acc[mi][ni], 0, 0, 0);
    __builtin_amdgcn_s_setprio(0);

    __builtin_amdgcn_sched_barrier(0);
    __builtin_amdgcn_s_barrier();            // all waves done reading buf[cur]
  }

#pragma unroll
  for (int mi = 0; mi < 4; ++mi) {
#pragma unroll
    for (int ni = 0; ni < 2; ++ni) {
      const int col = n0 + wc * 32 + ni * 16 + lr;
      const float bv = bias[col];
      const int rg0 = m0 + wr * 64 + mi * 16 + lg * 4;
      if (col >= 2048) {
        const int colv = col - 2048;
        const int dd = colv & 63, hh = colv >> 6;
        const int bb = rg0 >> 11, t = rg0 & 2047;
        union { bf16_t h4[4]; unsigned long long u; } pk;
#pragma unroll
        for (int r = 0; r < 4; ++r) pk.h4[r] = (bf16_t)(acc[mi][ni][r] + bv);
        *reinterpret_cast<unsigned long long*>(
            vtb + (size_t)(bb * 16 + hh) * 131072 + (size_t)dd * 2048 + t) = pk.u;
      } else {
        const float sc = (col < 1024) ? C2S : 1.f;
#pragma unroll
        for (int r = 0; r < 4; ++r) {
          const float v = (acc[mi][ni][r] + bv) * sc;
          outb[(size_t)(rg0 + r) * ldo + col] = (bf16_t)v;
        }
      }
    }
  }
}

// ---------------- Flash attention, split-KV x2, no-max softmax, 8-wave blocks ----
// (round-14/16 config: 4-buffer, single barrier/iter — verified)
__global__ __launch_bounds__(512) void attn_fwd(
    const bf16_t* __restrict__ qkv2,  // [4096][2048]  Q(scaled)|K
    const bf16_t* __restrict__ vT,    // [32][64][2048]
    bf16_t* __restrict__ a0, bf16_t* __restrict__ a1,  // [4096][1024] each
    float* __restrict__ lbuf) {       // [2][4096][16]
  __shared__ bf16_t lds[4][8192];
  const int tid = threadIdx.x;
  const int wave = tid >> 6, lane = tid & 63;
  const int lr = lane & 15, lg = lane >> 4;
  const int id = blockIdx.x;
  const int xcd = id & 7, slot = id >> 3;
  const int bh = xcd * 4 + (slot & 3);
  const int rest = slot >> 2;
  const int qb = rest & 7, kvh = rest >> 3;
  const int b = bh >> 4, h = bh & 15;

  const int q0 = qb * 256 + wave * 32;
  const bf16_t* Qp = qkv2 + (size_t)(b * 2048 + q0) * 2048 + h * 64;
  bf16x8 qf[2][2];
#pragma unroll
  for (int hx = 0; hx < 2; ++hx) {
    qf[hx][0] = *reinterpret_cast<const bf16x8*>(Qp + (size_t)(hx * 16 + lr) * 2048 + lg * 8);
    qf[hx][1] = *reinterpret_cast<const bf16x8*>(Qp + (size_t)(hx * 16 + lr) * 2048 + 32 + lg * 8);
  }

  const int kr = tid >> 3;
  const int ks = (tid & 7) ^ swz8(kr);
  const bf16_t* Ksrc = qkv2 + (size_t)(b * 2048 + kvh * 1024 + kr) * 2048 + 1024 + h * 64 + ks * 8;
  const bf16_t* Vsrc = vT + (size_t)bh * 131072 + (size_t)kr * 2048 + kvh * 1024 + ks * 8;

  auto stage = [&](int buf, int kb) {
    char* base = (char*)&lds[buf][0] + wave * 1024;
    gload16(Ksrc + (size_t)kb * 131072, base);
    gload16(Vsrc + (size_t)kb * 64, base + 8192);
  };

  int kofs[4][2], vofs[4][2];
#pragma unroll
  for (int t = 0; t < 4; ++t) {
    const int kk = 32 * (t >> 1) + 8 * (lr >> 2) + 4 * (t & 1) + (lr & 3);
    const int sw = swz8(kk) << 4;
    kofs[t][0] = (kk << 7) + ((lg * 16) ^ sw);
    kofs[t][1] = (kk << 7) + ((64 + lg * 16) ^ sw);
  }
#pragma unroll
  for (int nc = 0; nc < 4; ++nc) {
    const int vr = nc * 16 + lr;
    const int sw = swz8(vr) << 4;
    vofs[nc][0] = 8192 + (vr << 7) + ((lg * 16) ^ sw);
    vofs[nc][1] = 8192 + (vr << 7) + ((64 + lg * 16) ^ sw);
  }

  f32x4 acc[2][4] = {};
  f32x4 accl[2] = {};
  bf16x8 ones;
#pragma unroll
  for (int j = 0; j < 8; ++j) ones[j] = (bf16_t)1.0f;

  stage(0, 0);
  stage(1, 1);

  for (int kb = 0; kb < 16; ++kb) {
    const int cur = kb & 3;
    if (kb + 2 < 16) {
      stage((kb + 2) & 3, kb + 2);
      asm volatile("s_waitcnt vmcnt(4)" ::: "memory");
    } else if (kb + 1 < 16) {
      asm volatile("s_waitcnt vmcnt(2)" ::: "memory");
    } else {
      asm volatile("s_waitcnt vmcnt(0)" ::: "memory");
    }
    __builtin_amdgcn_s_barrier();
    __builtin_amdgcn_sched_barrier(0);
    const char* bK = (const char*)&lds[cur][0];

    f32x4 s[2][4];
#pragma unroll
    for (int t = 0; t < 4; ++t) {
      const bf16x8 k0 = *reinterpret_cast<const bf16x8*>(bK + kofs[t][0]);
      const bf16x8 k1 = *reinterpret_cast<const bf16x8*>(bK + kofs[t][1]);
#pragma unroll
      for (int hx = 0; hx < 2; ++hx) {
        f32x4 z = {0.f, 0.f, 0.f, 0.f};
        z = __builtin_amdgcn_mfma_f32_16x16x32_bf16(k0, qf[hx][0], z, 0, 0, 0);
        s[hx][t] = __builtin_amdgcn_mfma_f32_16x16x32_bf16(k1, qf[hx][1], z, 0, 0, 0);
      }
    }

    bf16x8 pa[2][2];
#pragma unroll
    for (int hx = 0; hx < 2; ++hx) {
      float p[16];
#pragma unroll
      for (int t = 0; t < 4; ++t)
#pragma unroll
        for (int r = 0; r < 4; ++r)
          p[t * 4 + r] = __builtin_amdgcn_exp2f(s[hx][t][r]);
#pragma unroll
      for (int j = 0; j < 8; ++j) { pa[hx][0][j] = (bf16_t)p[j]; pa[hx][1][j] = (bf16_t)p[8 + j]; }
    }

    __builtin_amdgcn_s_setprio(1);
#pragma unroll
    for (int hx = 0; hx < 2; ++hx) {
      accl[hx] = __builtin_amdgcn_mfma_f32_16x16x32_bf16(pa[hx][0], ones, accl[hx], 0, 0, 0);
      accl[hx] = __builtin_amdgcn_mfma_f32_16x16x32_bf16(pa[hx][1], ones, accl[hx], 0, 0, 0);
    }
#pragma unroll
    for (int nc = 0; nc < 4; ++nc) {
      const bf16x8 v0 = *reinterpret_cast<const bf16x8*>(bK + vofs[nc][0]);
      const bf16x8 v1 = *reinterpret_cast<const bf16x8*>(bK + vofs[nc][1]);
#pragma unroll
      for (int hx = 0; hx < 2; ++hx) {
        acc[hx][nc] = __builtin_amdgcn_mfma_f32_16x16x32_bf16(pa[hx][0], v0, acc[hx][nc], 0, 0, 0);
        acc[hx][nc] = __builtin_amdgcn_mfma_f32_16x16x32_bf16(pa[hx][1], v1, acc[hx][nc], 0, 0, 0);
      }
    }
    __builtin_amdgcn_s_setprio(0);
  }

  bf16_t* ap = kvh ? a1 : a0;
#pragma unroll
  for (int hx = 0; hx < 2; ++hx) {
#pragma unroll
    for (int r = 0; r < 4; ++r) {
      const float lf = 1.f / accl[hx][r];
      const int qg = q0 + hx * 16 + lg * 4 + r;
      bf16_t* op = ap + (size_t)(b * 2048 + qg) * 1024 + h * 64 + lr;
#pragma unroll
      for (int nc = 0; nc < 4; ++nc) op[nc * 16] = (bf16_t)(acc[hx][nc][r] * lf);
      if (lr == 0)
        lbuf[(size_t)(kvh * 4096 + b * 2048 + qg) * 16 + h] = accl[hx][r];
    }
  }
}

// ---------------- gemm2m: out = merge(a0,a1;lbuf) @ woutT^T + bias (f32) ----------------
// 64x128 tile, 512 threads = 8 waves (2x4), 16 waves/CU. Threads <256 do the
// A-merge; all 512 reg-stage B. LDS 24KB, grid 512.
__global__ __launch_bounds__(512) void gemm2m(
    const bf16_t* __restrict__ a0, const bf16_t* __restrict__ a1,
    const float* __restrict__ lbuf, const bf16_t* __restrict__ Bt,
    const float* __restrict__ bias, float* __restrict__ outf) {
  __shared__ bf16_t lA[2][2048];   // 64 x 32
  __shared__ bf16_t lB[2][4096];   // 128 x 32
  const int tid = threadIdx.x;
  const int wave = tid >> 6, lane = tid & 63;
  const int lr = lane & 15, lg = lane >> 4;
  const int bid = (blockIdx.x & 7) * 64 + (blockIdx.x >> 3);
  const int bm = bid >> 3, bn = bid & 7;
  const int m0 = bm * 64, n0 = bn * 128;
  const int wr = wave >> 2, wc = wave & 3;
  f32x4 acc[2][2] = {};

  const int srow = tid >> 2;
  const int scolb = ((tid & 3) << 4) ^ (((srow >> 1) & 3) << 4);
  const int scol = scolb >> 1;

  const bf16_t* pa0 = a0 + (size_t)(m0 + srow) * 1024 + scol;
  const bf16_t* pa1 = a1 + (size_t)(m0 + srow) * 1024 + scol;
  const float*  pl0 = lbuf + (size_t)(m0 + srow) * 16;
  const float*  pl1 = lbuf + (size_t)(4096 + m0 + srow) * 16;
  const bf16_t* pB0 = Bt + (size_t)(n0 + srow) * 1024 + scol;

  bf16x8 nA0 = {}, nA1 = {};
  float  nl0 = 1.f, nl1 = 1.f;
  if (tid < 256) {
    nA0 = *reinterpret_cast<const bf16x8*>(pa0);
    nA1 = *reinterpret_cast<const bf16x8*>(pa1);
    nl0 = pl0[0]; nl1 = pl1[0];
  }
  bf16x8 nB0v = *reinterpret_cast<const bf16x8*>(pB0);

  for (int t = 0; t < 32; ++t) {
    const int cur = t & 1;
    if (tid < 256) {
      const float inv = 1.f / (nl0 + nl1);
      const float w0 = nl0 * inv, w1 = nl1 * inv;
      bf16x8 mv;
#pragma unroll
      for (int j = 0; j < 8; ++j)
        mv[j] = (bf16_t)(w0 * (float)nA0[j] + w1 * (float)nA1[j]);
      *reinterpret_cast<bf16x8*>((char*)&lA[cur][0] + tid * 16) = mv;
    }
    *reinterpret_cast<bf16x8*>((char*)&lB[cur][0] + tid * 16) = nB0v;
    __syncthreads();

    if (t < 31) {
      const int k0 = (t + 1) * 32;
      const int h = k0 >> 6;
      if (tid < 256) {
        nA0 = *reinterpret_cast<const bf16x8*>(pa0 + k0);
        nA1 = *reinterpret_cast<const bf16x8*>(pa1 + k0);
        nl0 = pl0[h]; nl1 = pl1[h];
      }
      nB0v = *reinterpret_cast<const bf16x8*>(pB0 + k0);
    }

    const char* pA = (const char*)&lA[cur][0];
    const char* pB = (const char*)&lB[cur][0];
    bf16x8 af[2], bfv[2];
#pragma unroll
    for (int mi = 0; mi < 2; ++mi) {
      const int row = wr * 32 + mi * 16 + lr;
      af[mi] = *reinterpret_cast<const bf16x8*>(pA + row * 64 + ((lg * 16) ^ (((row >> 1) & 3) << 4)));
    }
#pragma unroll
    for (int ni = 0; ni < 2; ++ni) {
      const int row = wc * 32 + ni * 16 + lr;
      bfv[ni] = *reinterpret_cast<const bf16x8*>(pB + row * 64 + ((lg * 16) ^ (((row >> 1) & 3) << 4)));
    }
    __builtin_amdgcn_s_setprio(1);
#pragma unroll
    for (int mi = 0; mi < 2; ++mi)
#pragma unroll
      for (int ni = 0; ni < 2; ++ni)
        acc[mi][ni] = __builtin_amdgcn_mfma_f32_16x16x32_bf16(af[mi], bfv[ni], acc[mi][ni], 0, 0, 0);
    __builtin_amdgcn_s_setprio(0);
    __syncthreads();
  }

#pragma unroll
  for (int mi = 0; mi < 2; ++mi)
#pragma unroll
    for (int ni = 0; ni < 2; ++ni) {
      const int col = n0 + wc * 32 + ni * 16 + lr;
      const float bv = bias[col];
      const int rg0 = m0 + wr * 32 + mi * 16 + lg * 4;
#pragma unroll
      for (int r = 0; r < 4; ++r)
        outf[(size_t)(rg0 + r) * 1024 + col] = acc[mi][ni][r] + bv;
    }
}

extern "C" void kernel_launch(void* const* d_in, const int* in_sizes, int n_in,
                              void* d_out, int out_size, void* d_ws, size_t ws_size,
                              hipStream_t stream) {
  (void)in_sizes; (void)n_in; (void)out_size; (void)ws_size;
  const float* x    = (const float*)d_in[0];
  const float* Wqkv = (const float*)d_in[1];
  const float* bqkv = (const float*)d_in[2];
  const float* Wout = (const float*)d_in[3];
  const float* bout = (const float*)d_in[4];
  float* out = (float*)d_out;

  char* ws = (char*)d_ws;
  bf16_t* a0    = (bf16_t*)(ws);                 // [4096][1024]
  bf16_t* wqkvT = (bf16_t*)(ws + 8388608);       // [3072][1024]
  bf16_t* woutT = (bf16_t*)(ws + 14680064);      // [1024][1024]
  bf16_t* qkv2  = (bf16_t*)(ws + 16777216);      // [4096][2048] Q(scaled)|K
  bf16_t* vT    = (bf16_t*)(ws + 33554432);      // [32][64][2048]
  bf16_t* a1    = (bf16_t*)(ws + 41943040);      // [4096][1024]
  float*  lbuf  = (float*)(ws + 50331648);       // [2][4096][16]

  prep<<<4096, 256, 0, stream>>>(Wqkv, Wout, wqkvT, woutT);
  gemm8<<<768, 512, 0, stream>>>(x, wqkvT, bqkv, qkv2, vT, 3072, 1024, 2048);
  attn_fwd<<<512, 512, 0, stream>>>(qkv2, vT, a0, a1, lbuf);
  gemm2m<<<512, 512, 0, stream>>>(a0, a1, lbuf, woutT, bout, out);
}

// Round 20
// 109.806 us; speedup vs baseline: 1.0145x; 1.0145x over previous
//
#include <hip/hip_runtime.h>
#include <hip/hip_bf16.h>
#include <stdint.h>

typedef __bf16 bf16_t;
typedef __bf16 bf16x8 __attribute__((ext_vector_type(8)));
typedef float  f32x4  __attribute__((ext_vector_type(4)));

#define AS1 __attribute__((address_space(1)))
#define AS3 __attribute__((address_space(3)))

__device__ __forceinline__ void gload16(const bf16_t* g, char* l) {
  __builtin_amdgcn_global_load_lds((AS1 const void*)(uintptr_t)g, (AS3 void*)l, 16, 0, 0);
}
__device__ __forceinline__ int swz8(int r) { return (r & 7) ^ ((r >> 2) & 6); }

#define C2S 0.36067376022224085f   /* 0.25 * log2(e) */

// ---------------- prep: f32->bf16 convert of x  +  both weight transposes ----------------
__global__ __launch_bounds__(256) void prep(
    const float* __restrict__ x, const float* __restrict__ Wqkv, const float* __restrict__ Wout,
    bf16_t* __restrict__ xb, bf16_t* __restrict__ wqkvT, bf16_t* __restrict__ woutT) {
  __shared__ float tile[32][33];
  const int bid = blockIdx.x, tid = threadIdx.x;
  if (bid < 4096) {
    const int i = bid * 256 + tid;
    float4 v = reinterpret_cast<const float4*>(x)[i];
    union { bf16_t h[4]; unsigned long long u; } r;
    r.h[0] = (bf16_t)v.x; r.h[1] = (bf16_t)v.y; r.h[2] = (bf16_t)v.z; r.h[3] = (bf16_t)v.w;
    reinterpret_cast<unsigned long long*>(xb)[i] = r.u;
    return;
  }
  const float* W; bf16_t* Wt; int N, tb;
  if (bid < 7168) { W = Wqkv; Wt = wqkvT; N = 3072; tb = bid - 4096; }
  else            { W = Wout; Wt = woutT; N = 1024; tb = bid - 7168; }
  const int kb = (tb & 31) * 32, nb = (tb >> 5) * 32;
  const int tx = tid & 31, ty = tid >> 5;
#pragma unroll
  for (int i = 0; i < 32; i += 8)
    tile[ty + i][tx] = W[(size_t)(kb + ty + i) * N + nb + tx];
  __syncthreads();
  const int r = tid >> 3;
  const int c0 = (tid & 7) * 4;
  union { bf16_t h4[4]; unsigned long long u; } pk;
#pragma unroll
  for (int j = 0; j < 4; ++j) pk.h4[j] = (bf16_t)tile[c0 + j][r];
  *reinterpret_cast<unsigned long long*>(&Wt[(size_t)(nb + r) * 1024 + kb + c0]) = pk.u;
}

// ---------------- gemm8: 128x128 tile, BK=32, 8 waves (2x4) ----------------
// 3-buffer LDS (48KB, 3 blocks/CU), depth-2 prefetch, counted vmcnt 4/2/0.
// Rectangular XCD swizzle: 8 bm x 12 bn per XCD (A 2MB + B 3MB ~= L2).
__global__ __launch_bounds__(512) void gemm8(
    const bf16_t* __restrict__ A, const bf16_t* __restrict__ Bt,
    const float* __restrict__ bias,
    bf16_t* __restrict__ outb, bf16_t* __restrict__ vtb,
    int N, int K, int ldo) {
  __shared__ bf16_t lA[3][4096];
  __shared__ bf16_t lB[3][4096];
  const int tid = threadIdx.x;
  const int wave = tid >> 6, lane = tid & 63;
  const int lr = lane & 15, lg = lane >> 4;
  const int ntiles = N >> 7;
  int bm, bn;
  if (ntiles == 24) {
    const int xcd = blockIdx.x & 7, l = blockIdx.x >> 3;
    bm = (xcd >> 1) * 8 + (l & 7);
    bn = (xcd & 1) * 12 + (l >> 3);
  } else {
    const int bid = (blockIdx.x & 7) * ((int)gridDim.x >> 3) + (blockIdx.x >> 3);
    bn = bid % ntiles; bm = bid / ntiles;
  }
  const int m0 = bm * 128, n0 = bn * 128;
  const int wr = wave >> 2, wc = wave & 3;
  f32x4 acc[4][2] = {};

  const int srow = tid >> 2;                               // 0..127
  const int scolb = ((tid & 3) << 4) ^ (((srow >> 1) & 3) << 4);
  const bf16_t* Asrc = A  + (size_t)(m0 + srow) * K + (scolb >> 1);
  const bf16_t* Bsrc = Bt + (size_t)(n0 + srow) * K + (scolb >> 1);
  auto stage = [&](int buf, int k0) {
    gload16(Asrc + k0, (char*)&lA[buf][0] + wave * 1024);
    gload16(Bsrc + k0, (char*)&lB[buf][0] + wave * 1024);
  };

  auto ldA = [&](const char* p, int mi) {
    const int row = wr * 64 + mi * 16 + lr;
    return *reinterpret_cast<const bf16x8*>(p + row * 64 + ((lg * 16) ^ (((row >> 1) & 3) << 4)));
  };
  auto ldB = [&](const char* p, int ni) {
    const int row = wc * 32 + ni * 16 + lr;
    return *reinterpret_cast<const bf16x8*>(p + row * 64 + ((lg * 16) ^ (((row >> 1) & 3) << 4)));
  };

  const int nt = K >> 5;
  stage(0, 0);
  stage(1, 32);
  int cur = 0, stg = 2;

  for (int t = 0; t < nt; ++t) {
    if (t + 2 < nt) {
      stage(stg, (t + 2) << 5);
      asm volatile("s_waitcnt vmcnt(4)" ::: "memory");
    } else if (t + 1 < nt) {
      asm volatile("s_waitcnt vmcnt(2)" ::: "memory");
    } else {
      asm volatile("s_waitcnt vmcnt(0)" ::: "memory");
    }
    __builtin_amdgcn_s_barrier();
    __builtin_amdgcn_sched_barrier(0);

    const char* pA = (const char*)&lA[cur][0];
    const char* pB = (const char*)&lB[cur][0];
    bf16x8 af[4], bfv[2];
#pragma unroll
    for (int mi = 0; mi < 4; ++mi) af[mi] = ldA(pA, mi);
    bfv[0] = ldB(pB, 0); bfv[1] = ldB(pB, 1);

    __builtin_amdgcn_s_setprio(1);
#pragma unroll
    for (int mi = 0; mi < 4; ++mi)
#pragma unroll
      for (int ni = 0; ni < 2; ++ni)
        acc[mi][ni] = __builtin_amdgcn_mfma_f32_16x16x32_bf16(af[mi], bfv[ni], acc[mi][ni], 0, 0, 0);
    __builtin_amdgcn_s_setprio(0);

    __builtin_amdgcn_sched_barrier(0);
    __builtin_amdgcn_s_barrier();
    cur = cur == 2 ? 0 : cur + 1;
    stg = stg == 2 ? 0 : stg + 1;
  }

#pragma unroll
  for (int mi = 0; mi < 4; ++mi) {
#pragma unroll
    for (int ni = 0; ni < 2; ++ni) {
      const int col = n0 + wc * 32 + ni * 16 + lr;
      const float bv = bias[col];
      const int rg0 = m0 + wr * 64 + mi * 16 + lg * 4;
      if (col >= 2048) {
        const int colv = col - 2048;
        const int dd = colv & 63, hh = colv >> 6;
        const int bb = rg0 >> 11, t = rg0 & 2047;
        union { bf16_t h4[4]; unsigned long long u; } pk;
#pragma unroll
        for (int r = 0; r < 4; ++r) pk.h4[r] = (bf16_t)(acc[mi][ni][r] + bv);
        *reinterpret_cast<unsigned long long*>(
            vtb + (size_t)(bb * 16 + hh) * 131072 + (size_t)dd * 2048 + t) = pk.u;
      } else {
        const float sc = (col < 1024) ? C2S : 1.f;
#pragma unroll
        for (int r = 0; r < 4; ++r) {
          const float v = (acc[mi][ni][r] + bv) * sc;
          outb[(size_t)(rg0 + r) * ldo + col] = (bf16_t)v;
        }
      }
    }
  }
}

// ---------------- Flash attention, split-KV x2, no-max softmax, 8-wave blocks ----
// 2-buffer LDS (32KB -> 4 blocks/CU, max 32 waves/CU), depth-1, ONE barrier/iter.
// Race-free ordering: vmcnt(0) [stage(t) landed, issued a full body ago] ->
// publish barrier -> stage(t+1) into buf cur^1 (all waves past barrier have
// finished their iter-(t-1) reads of that buffer) -> compute(cur).
__global__ __launch_bounds__(512) void attn_fwd(
    const bf16_t* __restrict__ qkv2,  // [4096][2048]  Q(scaled)|K
    const bf16_t* __restrict__ vT,    // [32][64][2048]
    bf16_t* __restrict__ a0, bf16_t* __restrict__ a1,  // [4096][1024] each
    float* __restrict__ lbuf) {       // [2][4096][16]
  __shared__ bf16_t lds[2][8192];     // per buf 16KB: K [64k][64d] @0, V^T @8192
  const int tid = threadIdx.x;
  const int wave = tid >> 6, lane = tid & 63;
  const int lr = lane & 15, lg = lane >> 4;
  const int id = blockIdx.x;
  const int xcd = id & 7, slot = id >> 3;
  const int bh = xcd * 4 + (slot & 3);
  const int rest = slot >> 2;
  const int qb = rest & 7, kvh = rest >> 3;
  const int b = bh >> 4, h = bh & 15;

  const int q0 = qb * 256 + wave * 32;
  const bf16_t* Qp = qkv2 + (size_t)(b * 2048 + q0) * 2048 + h * 64;
  bf16x8 qf[2][2];
#pragma unroll
  for (int hx = 0; hx < 2; ++hx) {
    qf[hx][0] = *reinterpret_cast<const bf16x8*>(Qp + (size_t)(hx * 16 + lr) * 2048 + lg * 8);
    qf[hx][1] = *reinterpret_cast<const bf16x8*>(Qp + (size_t)(hx * 16 + lr) * 2048 + 32 + lg * 8);
  }

  const int kr = tid >> 3;
  const int ks = (tid & 7) ^ swz8(kr);
  const bf16_t* Ksrc = qkv2 + (size_t)(b * 2048 + kvh * 1024 + kr) * 2048 + 1024 + h * 64 + ks * 8;
  const bf16_t* Vsrc = vT + (size_t)bh * 131072 + (size_t)kr * 2048 + kvh * 1024 + ks * 8;

  auto stage = [&](int buf, int kb) {
    char* base = (char*)&lds[buf][0] + wave * 1024;
    gload16(Ksrc + (size_t)kb * 131072, base);
    gload16(Vsrc + (size_t)kb * 64, base + 8192);
  };

  int kofs[4][2], vofs[4][2];
#pragma unroll
  for (int t = 0; t < 4; ++t) {
    const int kk = 32 * (t >> 1) + 8 * (lr >> 2) + 4 * (t & 1) + (lr & 3);
    const int sw = swz8(kk) << 4;
    kofs[t][0] = (kk << 7) + ((lg * 16) ^ sw);
    kofs[t][1] = (kk << 7) + ((64 + lg * 16) ^ sw);
  }
#pragma unroll
  for (int nc = 0; nc < 4; ++nc) {
    const int vr = nc * 16 + lr;
    const int sw = swz8(vr) << 4;
    vofs[nc][0] = 8192 + (vr << 7) + ((lg * 16) ^ sw);
    vofs[nc][1] = 8192 + (vr << 7) + ((64 + lg * 16) ^ sw);
  }

  f32x4 acc[2][4] = {};
  f32x4 accl[2] = {};
  bf16x8 ones;
#pragma unroll
  for (int j = 0; j < 8; ++j) ones[j] = (bf16_t)1.0f;

  stage(0, 0);

  for (int kb = 0; kb < 16; ++kb) {
    const int cur = kb & 1;
    asm volatile("s_waitcnt vmcnt(0)" ::: "memory");   // stage(kb) landed (issued last iter)
    __builtin_amdgcn_s_barrier();                       // publish buf[cur]
    __builtin_amdgcn_sched_barrier(0);
    if (kb + 1 < 16) stage(cur ^ 1, kb + 1);            // safe after barrier
    const char* bK = (const char*)&lds[cur][0];

    f32x4 s[2][4];
#pragma unroll
    for (int t = 0; t < 4; ++t) {
      const bf16x8 k0 = *reinterpret_cast<const bf16x8*>(bK + kofs[t][0]);
      const bf16x8 k1 = *reinterpret_cast<const bf16x8*>(bK + kofs[t][1]);
#pragma unroll
      for (int hx = 0; hx < 2; ++hx) {
        f32x4 z = {0.f, 0.f, 0.f, 0.f};
        z = __builtin_amdgcn_mfma_f32_16x16x32_bf16(k0, qf[hx][0], z, 0, 0, 0);
        s[hx][t] = __builtin_amdgcn_mfma_f32_16x16x32_bf16(k1, qf[hx][1], z, 0, 0, 0);
      }
    }

    bf16x8 pa[2][2];
#pragma unroll
    for (int hx = 0; hx < 2; ++hx) {
      float p[16];
#pragma unroll
      for (int t = 0; t < 4; ++t)
#pragma unroll
        for (int r = 0; r < 4; ++r)
          p[t * 4 + r] = __builtin_amdgcn_exp2f(s[hx][t][r]);
#pragma unroll
      for (int j = 0; j < 8; ++j) { pa[hx][0][j] = (bf16_t)p[j]; pa[hx][1][j] = (bf16_t)p[8 + j]; }
    }

    __builtin_amdgcn_s_setprio(1);
#pragma unroll
    for (int hx = 0; hx < 2; ++hx) {
      accl[hx] = __builtin_amdgcn_mfma_f32_16x16x32_bf16(pa[hx][0], ones, accl[hx], 0, 0, 0);
      accl[hx] = __builtin_amdgcn_mfma_f32_16x16x32_bf16(pa[hx][1], ones, accl[hx], 0, 0, 0);
    }
#pragma unroll
    for (int nc = 0; nc < 4; ++nc) {
      const bf16x8 v0 = *reinterpret_cast<const bf16x8*>(bK + vofs[nc][0]);
      const bf16x8 v1 = *reinterpret_cast<const bf16x8*>(bK + vofs[nc][1]);
#pragma unroll
      for (int hx = 0; hx < 2; ++hx) {
        acc[hx][nc] = __builtin_amdgcn_mfma_f32_16x16x32_bf16(pa[hx][0], v0, acc[hx][nc], 0, 0, 0);
        acc[hx][nc] = __builtin_amdgcn_mfma_f32_16x16x32_bf16(pa[hx][1], v1, acc[hx][nc], 0, 0, 0);
      }
    }
    __builtin_amdgcn_s_setprio(0);
  }

  bf16_t* ap = kvh ? a1 : a0;
#pragma unroll
  for (int hx = 0; hx < 2; ++hx) {
#pragma unroll
    for (int r = 0; r < 4; ++r) {
      const float lf = 1.f / accl[hx][r];
      const int qg = q0 + hx * 16 + lg * 4 + r;
      bf16_t* op = ap + (size_t)(b * 2048 + qg) * 1024 + h * 64 + lr;
#pragma unroll
      for (int nc = 0; nc < 4; ++nc) op[nc * 16] = (bf16_t)(acc[hx][nc][r] * lf);
      if (lr == 0)
        lbuf[(size_t)(kvh * 4096 + b * 2048 + qg) * 16 + h] = accl[hx][r];
    }
  }
}

// ---------------- gemm2m: out = merge(a0,a1;lbuf) @ woutT^T + bias (f32) ----------------
// 64x128 tile, 512 threads = 8 waves (2x4). Threads <256 do the A-merge;
// all 512 reg-stage B. LDS 24KB, grid 512.
__global__ __launch_bounds__(512) void gemm2m(
    const bf16_t* __restrict__ a0, const bf16_t* __restrict__ a1,
    const float* __restrict__ lbuf, const bf16_t* __restrict__ Bt,
    const float* __restrict__ bias, float* __restrict__ outf) {
  __shared__ bf16_t lA[2][2048];   // 64 x 32
  __shared__ bf16_t lB[2][4096];   // 128 x 32
  const int tid = threadIdx.x;
  const int wave = tid >> 6, lane = tid & 63;
  const int lr = lane & 15, lg = lane >> 4;
  const int bid = (blockIdx.x & 7) * 64 + (blockIdx.x >> 3);
  const int bm = bid >> 3, bn = bid & 7;
  const int m0 = bm * 64, n0 = bn * 128;
  const int wr = wave >> 2, wc = wave & 3;
  f32x4 acc[2][2] = {};

  const int srow = tid >> 2;
  const int scolb = ((tid & 3) << 4) ^ (((srow >> 1) & 3) << 4);
  const int scol = scolb >> 1;

  const bf16_t* pa0 = a0 + (size_t)(m0 + srow) * 1024 + scol;
  const bf16_t* pa1 = a1 + (size_t)(m0 + srow) * 1024 + scol;
  const float*  pl0 = lbuf + (size_t)(m0 + srow) * 16;
  const float*  pl1 = lbuf + (size_t)(4096 + m0 + srow) * 16;
  const bf16_t* pB0 = Bt + (size_t)(n0 + srow) * 1024 + scol;

  bf16x8 nA0 = {}, nA1 = {};
  float  nl0 = 1.f, nl1 = 1.f;
  if (tid < 256) {
    nA0 = *reinterpret_cast<const bf16x8*>(pa0);
    nA1 = *reinterpret_cast<const bf16x8*>(pa1);
    nl0 = pl0[0]; nl1 = pl1[0];
  }
  bf16x8 nB0v = *reinterpret_cast<const bf16x8*>(pB0);

  for (int t = 0; t < 32; ++t) {
    const int cur = t & 1;
    if (tid < 256) {
      const float inv = 1.f / (nl0 + nl1);
      const float w0 = nl0 * inv, w1 = nl1 * inv;
      bf16x8 mv;
#pragma unroll
      for (int j = 0; j < 8; ++j)
        mv[j] = (bf16_t)(w0 * (float)nA0[j] + w1 * (float)nA1[j]);
      *reinterpret_cast<bf16x8*>((char*)&lA[cur][0] + tid * 16) = mv;
    }
    *reinterpret_cast<bf16x8*>((char*)&lB[cur][0] + tid * 16) = nB0v;
    __syncthreads();

    if (t < 31) {
      const int k0 = (t + 1) * 32;
      const int h = k0 >> 6;
      if (tid < 256) {
        nA0 = *reinterpret_cast<const bf16x8*>(pa0 + k0);
        nA1 = *reinterpret_cast<const bf16x8*>(pa1 + k0);
        nl0 = pl0[h]; nl1 = pl1[h];
      }
      nB0v = *reinterpret_cast<const bf16x8*>(pB0 + k0);
    }

    const char* pA = (const char*)&lA[cur][0];
    const char* pB = (const char*)&lB[cur][0];
    bf16x8 af[2], bfv[2];
#pragma unroll
    for (int mi = 0; mi < 2; ++mi) {
      const int row = wr * 32 + mi * 16 + lr;
      af[mi] = *reinterpret_cast<const bf16x8*>(pA + row * 64 + ((lg * 16) ^ (((row >> 1) & 3) << 4)));
    }
#pragma unroll
    for (int ni = 0; ni < 2; ++ni) {
      const int row = wc * 32 + ni * 16 + lr;
      bfv[ni] = *reinterpret_cast<const bf16x8*>(pB + row * 64 + ((lg * 16) ^ (((row >> 1) & 3) << 4)));
    }
    __builtin_amdgcn_s_setprio(1);
#pragma unroll
    for (int mi = 0; mi < 2; ++mi)
#pragma unroll
      for (int ni = 0; ni < 2; ++ni)
        acc[mi][ni] = __builtin_amdgcn_mfma_f32_16x16x32_bf16(af[mi], bfv[ni], acc[mi][ni], 0, 0, 0);
    __builtin_amdgcn_s_setprio(0);
    __syncthreads();
  }

#pragma unroll
  for (int mi = 0; mi < 2; ++mi)
#pragma unroll
    for (int ni = 0; ni < 2; ++ni) {
      const int col = n0 + wc * 32 + ni * 16 + lr;
      const float bv = bias[col];
      const int rg0 = m0 + wr * 32 + mi * 16 + lg * 4;
#pragma unroll
      for (int r = 0; r < 4; ++r)
        outf[(size_t)(rg0 + r) * 1024 + col] = acc[mi][ni][r] + bv;
    }
}

extern "C" void kernel_launch(void* const* d_in, const int* in_sizes, int n_in,
                              void* d_out, int out_size, void* d_ws, size_t ws_size,
                              hipStream_t stream) {
  (void)in_sizes; (void)n_in; (void)out_size; (void)ws_size;
  const float* x    = (const float*)d_in[0];
  const float* Wqkv = (const float*)d_in[1];
  const float* bqkv = (const float*)d_in[2];
  const float* Wout = (const float*)d_in[3];
  const float* bout = (const float*)d_in[4];
  float* out = (float*)d_out;

  char* ws = (char*)d_ws;
  bf16_t* xb    = (bf16_t*)(ws);
  bf16_t* a0    = (bf16_t*)(ws);
  bf16_t* wqkvT = (bf16_t*)(ws + 8388608);
  bf16_t* woutT = (bf16_t*)(ws + 14680064);
  bf16_t* qkv2  = (bf16_t*)(ws + 16777216);
  bf16_t* vT    = (bf16_t*)(ws + 33554432);
  bf16_t* a1    = (bf16_t*)(ws + 41943040);
  float*  lbuf  = (float*)(ws + 50331648);

  prep<<<8192, 256, 0, stream>>>(x, Wqkv, Wout, xb, wqkvT, woutT);
  gemm8<<<768, 512, 0, stream>>>(xb, wqkvT, bqkv, qkv2, vT, 3072, 1024, 2048);
  attn_fwd<<<512, 512, 0, stream>>>(qkv2, vT, a0, a1, lbuf);
  gemm2m<<<512, 512, 0, stream>>>(a0, a1, lbuf, woutT, bout, out);
}

// Round 21
// 108.651 us; speedup vs baseline: 1.0253x; 1.0106x over previous
//
#include <hip/hip_runtime.h>
#include <hip/hip_bf16.h>
#include <stdint.h>

typedef __bf16 bf16_t;
typedef __bf16 bf16x8 __attribute__((ext_vector_type(8)));
typedef float  f32x4  __attribute__((ext_vector_type(4)));

#define AS1 __attribute__((address_space(1)))
#define AS3 __attribute__((address_space(3)))

__device__ __forceinline__ void gload16(const bf16_t* g, char* l) {
  __builtin_amdgcn_global_load_lds((AS1 const void*)(uintptr_t)g, (AS3 void*)l, 16, 0, 0);
}
__device__ __forceinline__ int swz8(int r) { return (r & 7) ^ ((r >> 2) & 6); }

#define C2S 0.36067376022224085f   /* 0.25 * log2(e) */

// ---------------- prep: f32->bf16 convert of x  +  both weight transposes ----------------
__global__ __launch_bounds__(256) void prep(
    const float* __restrict__ x, const float* __restrict__ Wqkv, const float* __restrict__ Wout,
    bf16_t* __restrict__ xb, bf16_t* __restrict__ wqkvT, bf16_t* __restrict__ woutT) {
  __shared__ float tile[32][33];
  const int bid = blockIdx.x, tid = threadIdx.x;
  if (bid < 4096) {
    const int i = bid * 256 + tid;
    float4 v = reinterpret_cast<const float4*>(x)[i];
    union { bf16_t h[4]; unsigned long long u; } r;
    r.h[0] = (bf16_t)v.x; r.h[1] = (bf16_t)v.y; r.h[2] = (bf16_t)v.z; r.h[3] = (bf16_t)v.w;
    reinterpret_cast<unsigned long long*>(xb)[i] = r.u;
    return;
  }
  const float* W; bf16_t* Wt; int N, tb;
  if (bid < 7168) { W = Wqkv; Wt = wqkvT; N = 3072; tb = bid - 4096; }
  else            { W = Wout; Wt = woutT; N = 1024; tb = bid - 7168; }
  const int kb = (tb & 31) * 32, nb = (tb >> 5) * 32;
  const int tx = tid & 31, ty = tid >> 5;
#pragma unroll
  for (int i = 0; i < 32; i += 8)
    tile[ty + i][tx] = W[(size_t)(kb + ty + i) * N + nb + tx];
  __syncthreads();
  const int r = tid >> 3;
  const int c0 = (tid & 7) * 4;
  union { bf16_t h4[4]; unsigned long long u; } pk;
#pragma unroll
  for (int j = 0; j < 4; ++j) pk.h4[j] = (bf16_t)tile[c0 + j][r];
  *reinterpret_cast<unsigned long long*>(&Wt[(size_t)(nb + r) * 1024 + kb + c0]) = pk.u;
}

// ---------------- gemm8: 128x128 tile, BK=32, 8 waves (2x4) ----------------
// 2-buffer LDS (32KB -> 4 blocks/CU, 32 waves/CU), depth-1, ONE barrier/iter:
// vmcnt(0) [stage(t) issued a full body ago] -> publish barrier -> stage(t+1)
// into buf cur^1 (race-free: all waves past barrier finished iter-(t-1) reads)
// -> ds_read + MFMA. Rectangular XCD swizzle (8bm x 12bn / XCD).
__global__ __launch_bounds__(512) void gemm8(
    const bf16_t* __restrict__ A, const bf16_t* __restrict__ Bt,
    const float* __restrict__ bias,
    bf16_t* __restrict__ outb, bf16_t* __restrict__ vtb,
    int N, int K, int ldo) {
  __shared__ bf16_t lA[2][4096];
  __shared__ bf16_t lB[2][4096];
  const int tid = threadIdx.x;
  const int wave = tid >> 6, lane = tid & 63;
  const int lr = lane & 15, lg = lane >> 4;
  const int ntiles = N >> 7;
  int bm, bn;
  if (ntiles == 24) {
    const int xcd = blockIdx.x & 7, l = blockIdx.x >> 3;
    bm = (xcd >> 1) * 8 + (l & 7);
    bn = (xcd & 1) * 12 + (l >> 3);
  } else {
    const int bid = (blockIdx.x & 7) * ((int)gridDim.x >> 3) + (blockIdx.x >> 3);
    bn = bid % ntiles; bm = bid / ntiles;
  }
  const int m0 = bm * 128, n0 = bn * 128;
  const int wr = wave >> 2, wc = wave & 3;
  f32x4 acc[4][2] = {};

  const int srow = tid >> 2;                               // 0..127
  const int scolb = ((tid & 3) << 4) ^ (((srow >> 1) & 3) << 4);
  const bf16_t* Asrc = A  + (size_t)(m0 + srow) * K + (scolb >> 1);
  const bf16_t* Bsrc = Bt + (size_t)(n0 + srow) * K + (scolb >> 1);
  auto stage = [&](int buf, int k0) {
    gload16(Asrc + k0, (char*)&lA[buf][0] + wave * 1024);
    gload16(Bsrc + k0, (char*)&lB[buf][0] + wave * 1024);
  };

  auto ldA = [&](const char* p, int mi) {
    const int row = wr * 64 + mi * 16 + lr;
    return *reinterpret_cast<const bf16x8*>(p + row * 64 + ((lg * 16) ^ (((row >> 1) & 3) << 4)));
  };
  auto ldB = [&](const char* p, int ni) {
    const int row = wc * 32 + ni * 16 + lr;
    return *reinterpret_cast<const bf16x8*>(p + row * 64 + ((lg * 16) ^ (((row >> 1) & 3) << 4)));
  };

  const int nt = K >> 5;
  stage(0, 0);

  for (int t = 0; t < nt; ++t) {
    const int cur = t & 1;
    asm volatile("s_waitcnt vmcnt(0)" ::: "memory");   // stage(t) landed
    __builtin_amdgcn_s_barrier();                       // publish buf[cur]
    __builtin_amdgcn_sched_barrier(0);
    if (t + 1 < nt) stage(cur ^ 1, (t + 1) << 5);       // safe after barrier

    const char* pA = (const char*)&lA[cur][0];
    const char* pB = (const char*)&lB[cur][0];
    bf16x8 af[4], bfv[2];
#pragma unroll
    for (int mi = 0; mi < 4; ++mi) af[mi] = ldA(pA, mi);
    bfv[0] = ldB(pB, 0); bfv[1] = ldB(pB, 1);

    __builtin_amdgcn_s_setprio(1);
#pragma unroll
    for (int mi = 0; mi < 4; ++mi)
#pragma unroll
      for (int ni = 0; ni < 2; ++ni)
        acc[mi][ni] = __builtin_amdgcn_mfma_f32_16x16x32_bf16(af[mi], bfv[ni], acc[mi][ni], 0, 0, 0);
    __builtin_amdgcn_s_setprio(0);
  }

#pragma unroll
  for (int mi = 0; mi < 4; ++mi) {
#pragma unroll
    for (int ni = 0; ni < 2; ++ni) {
      const int col = n0 + wc * 32 + ni * 16 + lr;
      const float bv = bias[col];
      const int rg0 = m0 + wr * 64 + mi * 16 + lg * 4;
      if (col >= 2048) {
        const int colv = col - 2048;
        const int dd = colv & 63, hh = colv >> 6;
        const int bb = rg0 >> 11, t = rg0 & 2047;
        union { bf16_t h4[4]; unsigned long long u; } pk;
#pragma unroll
        for (int r = 0; r < 4; ++r) pk.h4[r] = (bf16_t)(acc[mi][ni][r] + bv);
        *reinterpret_cast<unsigned long long*>(
            vtb + (size_t)(bb * 16 + hh) * 131072 + (size_t)dd * 2048 + t) = pk.u;
      } else {
        const float sc = (col < 1024) ? C2S : 1.f;
#pragma unroll
        for (int r = 0; r < 4; ++r) {
          const float v = (acc[mi][ni][r] + bv) * sc;
          outb[(size_t)(rg0 + r) * ldo + col] = (bf16_t)v;
        }
      }
    }
  }
}

// ---------------- Flash attention, split-KV x2, no-max softmax, 8-wave blocks ----
// 2-buffer LDS (32KB -> 4 blocks/CU), depth-1, ONE barrier/iter (r20 verified).
__global__ __launch_bounds__(512) void attn_fwd(
    const bf16_t* __restrict__ qkv2,  // [4096][2048]  Q(scaled)|K
    const bf16_t* __restrict__ vT,    // [32][64][2048]
    bf16_t* __restrict__ a0, bf16_t* __restrict__ a1,  // [4096][1024] each
    float* __restrict__ lbuf) {       // [2][4096][16]
  __shared__ bf16_t lds[2][8192];     // per buf 16KB: K [64k][64d] @0, V^T @8192
  const int tid = threadIdx.x;
  const int wave = tid >> 6, lane = tid & 63;
  const int lr = lane & 15, lg = lane >> 4;
  const int id = blockIdx.x;
  const int xcd = id & 7, slot = id >> 3;
  const int bh = xcd * 4 + (slot & 3);
  const int rest = slot >> 2;
  const int qb = rest & 7, kvh = rest >> 3;
  const int b = bh >> 4, h = bh & 15;

  const int q0 = qb * 256 + wave * 32;
  const bf16_t* Qp = qkv2 + (size_t)(b * 2048 + q0) * 2048 + h * 64;
  bf16x8 qf[2][2];
#pragma unroll
  for (int hx = 0; hx < 2; ++hx) {
    qf[hx][0] = *reinterpret_cast<const bf16x8*>(Qp + (size_t)(hx * 16 + lr) * 2048 + lg * 8);
    qf[hx][1] = *reinterpret_cast<const bf16x8*>(Qp + (size_t)(hx * 16 + lr) * 2048 + 32 + lg * 8);
  }

  const int kr = tid >> 3;
  const int ks = (tid & 7) ^ swz8(kr);
  const bf16_t* Ksrc = qkv2 + (size_t)(b * 2048 + kvh * 1024 + kr) * 2048 + 1024 + h * 64 + ks * 8;
  const bf16_t* Vsrc = vT + (size_t)bh * 131072 + (size_t)kr * 2048 + kvh * 1024 + ks * 8;

  auto stage = [&](int buf, int kb) {
    char* base = (char*)&lds[buf][0] + wave * 1024;
    gload16(Ksrc + (size_t)kb * 131072, base);
    gload16(Vsrc + (size_t)kb * 64, base + 8192);
  };

  int kofs[4][2], vofs[4][2];
#pragma unroll
  for (int t = 0; t < 4; ++t) {
    const int kk = 32 * (t >> 1) + 8 * (lr >> 2) + 4 * (t & 1) + (lr & 3);
    const int sw = swz8(kk) << 4;
    kofs[t][0] = (kk << 7) + ((lg * 16) ^ sw);
    kofs[t][1] = (kk << 7) + ((64 + lg * 16) ^ sw);
  }
#pragma unroll
  for (int nc = 0; nc < 4; ++nc) {
    const int vr = nc * 16 + lr;
    const int sw = swz8(vr) << 4;
    vofs[nc][0] = 8192 + (vr << 7) + ((lg * 16) ^ sw);
    vofs[nc][1] = 8192 + (vr << 7) + ((64 + lg * 16) ^ sw);
  }

  f32x4 acc[2][4] = {};
  f32x4 accl[2] = {};
  bf16x8 ones;
#pragma unroll
  for (int j = 0; j < 8; ++j) ones[j] = (bf16_t)1.0f;

  stage(0, 0);

  for (int kb = 0; kb < 16; ++kb) {
    const int cur = kb & 1;
    asm volatile("s_waitcnt vmcnt(0)" ::: "memory");
    __builtin_amdgcn_s_barrier();
    __builtin_amdgcn_sched_barrier(0);
    if (kb + 1 < 16) stage(cur ^ 1, kb + 1);
    const char* bK = (const char*)&lds[cur][0];

    f32x4 s[2][4];
#pragma unroll
    for (int t = 0; t < 4; ++t) {
      const bf16x8 k0 = *reinterpret_cast<const bf16x8*>(bK + kofs[t][0]);
      const bf16x8 k1 = *reinterpret_cast<const bf16x8*>(bK + kofs[t][1]);
#pragma unroll
      for (int hx = 0; hx < 2; ++hx) {
        f32x4 z = {0.f, 0.f, 0.f, 0.f};
        z = __builtin_amdgcn_mfma_f32_16x16x32_bf16(k0, qf[hx][0], z, 0, 0, 0);
        s[hx][t] = __builtin_amdgcn_mfma_f32_16x16x32_bf16(k1, qf[hx][1], z, 0, 0, 0);
      }
    }

    bf16x8 pa[2][2];
#pragma unroll
    for (int hx = 0; hx < 2; ++hx) {
      float p[16];
#pragma unroll
      for (int t = 0; t < 4; ++t)
#pragma unroll
        for (int r = 0; r < 4; ++r)
          p[t * 4 + r] = __builtin_amdgcn_exp2f(s[hx][t][r]);
#pragma unroll
      for (int j = 0; j < 8; ++j) { pa[hx][0][j] = (bf16_t)p[j]; pa[hx][1][j] = (bf16_t)p[8 + j]; }
    }

    __builtin_amdgcn_s_setprio(1);
#pragma unroll
    for (int hx = 0; hx < 2; ++hx) {
      accl[hx] = __builtin_amdgcn_mfma_f32_16x16x32_bf16(pa[hx][0], ones, accl[hx], 0, 0, 0);
      accl[hx] = __builtin_amdgcn_mfma_f32_16x16x32_bf16(pa[hx][1], ones, accl[hx], 0, 0, 0);
    }
#pragma unroll
    for (int nc = 0; nc < 4; ++nc) {
      const bf16x8 v0 = *reinterpret_cast<const bf16x8*>(bK + vofs[nc][0]);
      const bf16x8 v1 = *reinterpret_cast<const bf16x8*>(bK + vofs[nc][1]);
#pragma unroll
      for (int hx = 0; hx < 2; ++hx) {
        acc[hx][nc] = __builtin_amdgcn_mfma_f32_16x16x32_bf16(pa[hx][0], v0, acc[hx][nc], 0, 0, 0);
        acc[hx][nc] = __builtin_amdgcn_mfma_f32_16x16x32_bf16(pa[hx][1], v1, acc[hx][nc], 0, 0, 0);
      }
    }
    __builtin_amdgcn_s_setprio(0);
  }

  bf16_t* ap = kvh ? a1 : a0;
#pragma unroll
  for (int hx = 0; hx < 2; ++hx) {
#pragma unroll
    for (int r = 0; r < 4; ++r) {
      const float lf = 1.f / accl[hx][r];
      const int qg = q0 + hx * 16 + lg * 4 + r;
      bf16_t* op = ap + (size_t)(b * 2048 + qg) * 1024 + h * 64 + lr;
#pragma unroll
      for (int nc = 0; nc < 4; ++nc) op[nc * 16] = (bf16_t)(acc[hx][nc][r] * lf);
      if (lr == 0)
        lbuf[(size_t)(kvh * 4096 + b * 2048 + qg) * 16 + h] = accl[hx][r];
    }
  }
}

// ---------------- gemm2m: out = merge(a0,a1;lbuf) @ woutT^T + bias (f32) ----------------
// 64x128 tile, 512 threads = 8 waves (2x4). Threads <256 do the A-merge;
// all 512 reg-stage B. LDS 24KB, grid 512.
__global__ __launch_bounds__(512) void gemm2m(
    const bf16_t* __restrict__ a0, const bf16_t* __restrict__ a1,
    const float* __restrict__ lbuf, const bf16_t* __restrict__ Bt,
    const float* __restrict__ bias, float* __restrict__ outf) {
  __shared__ bf16_t lA[2][2048];   // 64 x 32
  __shared__ bf16_t lB[2][4096];   // 128 x 32
  const int tid = threadIdx.x;
  const int wave = tid >> 6, lane = tid & 63;
  const int lr = lane & 15, lg = lane >> 4;
  const int bid = (blockIdx.x & 7) * 64 + (blockIdx.x >> 3);
  const int bm = bid >> 3, bn = bid & 7;
  const int m0 = bm * 64, n0 = bn * 128;
  const int wr = wave >> 2, wc = wave & 3;
  f32x4 acc[2][2] = {};

  const int srow = tid >> 2;
  const int scolb = ((tid & 3) << 4) ^ (((srow >> 1) & 3) << 4);
  const int scol = scolb >> 1;

  const bf16_t* pa0 = a0 + (size_t)(m0 + srow) * 1024 + scol;
  const bf16_t* pa1 = a1 + (size_t)(m0 + srow) * 1024 + scol;
  const float*  pl0 = lbuf + (size_t)(m0 + srow) * 16;
  const float*  pl1 = lbuf + (size_t)(4096 + m0 + srow) * 16;
  const bf16_t* pB0 = Bt + (size_t)(n0 + srow) * 1024 + scol;

  bf16x8 nA0 = {}, nA1 = {};
  float  nl0 = 1.f, nl1 = 1.f;
  if (tid < 256) {
    nA0 = *reinterpret_cast<const bf16x8*>(pa0);
    nA1 = *reinterpret_cast<const bf16x8*>(pa1);
    nl0 = pl0[0]; nl1 = pl1[0];
  }
  bf16x8 nB0v = *reinterpret_cast<const bf16x8*>(pB0);

  for (int t = 0; t < 32; ++t) {
    const int cur = t & 1;
    if (tid < 256) {
      const float inv = 1.f / (nl0 + nl1);
      const float w0 = nl0 * inv, w1 = nl1 * inv;
      bf16x8 mv;
#pragma unroll
      for (int j = 0; j < 8; ++j)
        mv[j] = (bf16_t)(w0 * (float)nA0[j] + w1 * (float)nA1[j]);
      *reinterpret_cast<bf16x8*>((char*)&lA[cur][0] + tid * 16) = mv;
    }
    *reinterpret_cast<bf16x8*>((char*)&lB[cur][0] + tid * 16) = nB0v;
    __syncthreads();

    if (t < 31) {
      const int k0 = (t + 1) * 32;
      const int h = k0 >> 6;
      if (tid < 256) {
        nA0 = *reinterpret_cast<const bf16x8*>(pa0 + k0);
        nA1 = *reinterpret_cast<const bf16x8*>(pa1 + k0);
        nl0 = pl0[h]; nl1 = pl1[h];
      }
      nB0v = *reinterpret_cast<const bf16x8*>(pB0 + k0);
    }

    const char* pA = (const char*)&lA[cur][0];
    const char* pB = (const char*)&lB[cur][0];
    bf16x8 af[2], bfv[2];
#pragma unroll
    for (int mi = 0; mi < 2; ++mi) {
      const int row = wr * 32 + mi * 16 + lr;
      af[mi] = *reinterpret_cast<const bf16x8*>(pA + row * 64 + ((lg * 16) ^ (((row >> 1) & 3) << 4)));
    }
#pragma unroll
    for (int ni = 0; ni < 2; ++ni) {
      const int row = wc * 32 + ni * 16 + lr;
      bfv[ni] = *reinterpret_cast<const bf16x8*>(pB + row * 64 + ((lg * 16) ^ (((row >> 1) & 3) << 4)));
    }
    __builtin_amdgcn_s_setprio(1);
#pragma unroll
    for (int mi = 0; mi < 2; ++mi)
#pragma unroll
      for (int ni = 0; ni < 2; ++ni)
        acc[mi][ni] = __builtin_amdgcn_mfma_f32_16x16x32_bf16(af[mi], bfv[ni], acc[mi][ni], 0, 0, 0);
    __builtin_amdgcn_s_setprio(0);
    __syncthreads();
  }

#pragma unroll
  for (int mi = 0; mi < 2; ++mi)
#pragma unroll
    for (int ni = 0; ni < 2; ++ni) {
      const int col = n0 + wc * 32 + ni * 16 + lr;
      const float bv = bias[col];
      const int rg0 = m0 + wr * 32 + mi * 16 + lg * 4;
#pragma unroll
      for (int r = 0; r < 4; ++r)
        outf[(size_t)(rg0 + r) * 1024 + col] = acc[mi][ni][r] + bv;
    }
}

extern "C" void kernel_launch(void* const* d_in, const int* in_sizes, int n_in,
                              void* d_out, int out_size, void* d_ws, size_t ws_size,
                              hipStream_t stream) {
  (void)in_sizes; (void)n_in; (void)out_size; (void)ws_size;
  const float* x    = (const float*)d_in[0];
  const float* Wqkv = (const float*)d_in[1];
  const float* bqkv = (const float*)d_in[2];
  const float* Wout = (const float*)d_in[3];
  const float* bout = (const float*)d_in[4];
  float* out = (float*)d_out;

  char* ws = (char*)d_ws;
  bf16_t* xb    = (bf16_t*)(ws);
  bf16_t* a0    = (bf16_t*)(ws);
  bf16_t* wqkvT = (bf16_t*)(ws + 8388608);
  bf16_t* woutT = (bf16_t*)(ws + 14680064);
  bf16_t* qkv2  = (bf16_t*)(ws + 16777216);
  bf16_t* vT    = (bf16_t*)(ws + 33554432);
  bf16_t* a1    = (bf16_t*)(ws + 41943040);
  float*  lbuf  = (float*)(ws + 50331648);

  prep<<<8192, 256, 0, stream>>>(x, Wqkv, Wout, xb, wqkvT, woutT);
  gemm8<<<768, 512, 0, stream>>>(xb, wqkvT, bqkv, qkv2, vT, 3072, 1024, 2048);
  attn_fwd<<<512, 512, 0, stream>>>(qkv2, vT, a0, a1, lbuf);
  gemm2m<<<512, 512, 0, stream>>>(a0, a1, lbuf, woutT, bout, out);
}

// Round 22
// 108.645 us; speedup vs baseline: 1.0254x; 1.0001x over previous
//
#include <hip/hip_runtime.h>
#include <hip/hip_bf16.h>
#include <stdint.h>

typedef __bf16 bf16_t;
typedef __bf16 bf16x8 __attribute__((ext_vector_type(8)));
typedef float  f32x4  __attribute__((ext_vector_type(4)));

#define AS1 __attribute__((address_space(1)))
#define AS3 __attribute__((address_space(3)))

__device__ __forceinline__ void gload16(const bf16_t* g, char* l) {
  __builtin_amdgcn_global_load_lds((AS1 const void*)(uintptr_t)g, (AS3 void*)l, 16, 0, 0);
}
__device__ __forceinline__ int swz8(int r) { return (r & 7) ^ ((r >> 2) & 6); }

#define C2S 0.36067376022224085f   /* 0.25 * log2(e) */

// ---------------- prep: f32->bf16 convert of x  +  both weight transposes ----------------
__global__ __launch_bounds__(256) void prep(
    const float* __restrict__ x, const float* __restrict__ Wqkv, const float* __restrict__ Wout,
    bf16_t* __restrict__ xb, bf16_t* __restrict__ wqkvT, bf16_t* __restrict__ woutT) {
  __shared__ float tile[32][33];
  const int bid = blockIdx.x, tid = threadIdx.x;
  if (bid < 4096) {
    const int i = bid * 256 + tid;
    float4 v = reinterpret_cast<const float4*>(x)[i];
    union { bf16_t h[4]; unsigned long long u; } r;
    r.h[0] = (bf16_t)v.x; r.h[1] = (bf16_t)v.y; r.h[2] = (bf16_t)v.z; r.h[3] = (bf16_t)v.w;
    reinterpret_cast<unsigned long long*>(xb)[i] = r.u;
    return;
  }
  const float* W; bf16_t* Wt; int N, tb;
  if (bid < 7168) { W = Wqkv; Wt = wqkvT; N = 3072; tb = bid - 4096; }
  else            { W = Wout; Wt = woutT; N = 1024; tb = bid - 7168; }
  const int kb = (tb & 31) * 32, nb = (tb >> 5) * 32;
  const int tx = tid & 31, ty = tid >> 5;
#pragma unroll
  for (int i = 0; i < 32; i += 8)
    tile[ty + i][tx] = W[(size_t)(kb + ty + i) * N + nb + tx];
  __syncthreads();
  const int r = tid >> 3;
  const int c0 = (tid & 7) * 4;
  union { bf16_t h4[4]; unsigned long long u; } pk;
#pragma unroll
  for (int j = 0; j < 4; ++j) pk.h4[j] = (bf16_t)tile[c0 + j][r];
  *reinterpret_cast<unsigned long long*>(&Wt[(size_t)(nb + r) * 1024 + kb + c0]) = pk.u;
}

// ---------------- gemm8: 128x128 tile, BK=32, 8 waves (2x4) ----------------
// 2-buffer LDS (32KB -> 4 blocks/CU), depth-1, ONE barrier/iter (r21 verified).
__global__ __launch_bounds__(512) void gemm8(
    const bf16_t* __restrict__ A, const bf16_t* __restrict__ Bt,
    const float* __restrict__ bias,
    bf16_t* __restrict__ outb, bf16_t* __restrict__ vtb,
    int N, int K, int ldo) {
  __shared__ bf16_t lA[2][4096];
  __shared__ bf16_t lB[2][4096];
  const int tid = threadIdx.x;
  const int wave = tid >> 6, lane = tid & 63;
  const int lr = lane & 15, lg = lane >> 4;
  const int ntiles = N >> 7;
  int bm, bn;
  if (ntiles == 24) {
    const int xcd = blockIdx.x & 7, l = blockIdx.x >> 3;
    bm = (xcd >> 1) * 8 + (l & 7);
    bn = (xcd & 1) * 12 + (l >> 3);
  } else {
    const int bid = (blockIdx.x & 7) * ((int)gridDim.x >> 3) + (blockIdx.x >> 3);
    bn = bid % ntiles; bm = bid / ntiles;
  }
  const int m0 = bm * 128, n0 = bn * 128;
  const int wr = wave >> 2, wc = wave & 3;
  f32x4 acc[4][2] = {};

  const int srow = tid >> 2;                               // 0..127
  const int scolb = ((tid & 3) << 4) ^ (((srow >> 1) & 3) << 4);
  const bf16_t* Asrc = A  + (size_t)(m0 + srow) * K + (scolb >> 1);
  const bf16_t* Bsrc = Bt + (size_t)(n0 + srow) * K + (scolb >> 1);
  auto stage = [&](int buf, int k0) {
    gload16(Asrc + k0, (char*)&lA[buf][0] + wave * 1024);
    gload16(Bsrc + k0, (char*)&lB[buf][0] + wave * 1024);
  };

  auto ldA = [&](const char* p, int mi) {
    const int row = wr * 64 + mi * 16 + lr;
    return *reinterpret_cast<const bf16x8*>(p + row * 64 + ((lg * 16) ^ (((row >> 1) & 3) << 4)));
  };
  auto ldB = [&](const char* p, int ni) {
    const int row = wc * 32 + ni * 16 + lr;
    return *reinterpret_cast<const bf16x8*>(p + row * 64 + ((lg * 16) ^ (((row >> 1) & 3) << 4)));
  };

  const int nt = K >> 5;
  stage(0, 0);

  for (int t = 0; t < nt; ++t) {
    const int cur = t & 1;
    asm volatile("s_waitcnt vmcnt(0)" ::: "memory");   // stage(t) landed
    __builtin_amdgcn_s_barrier();                       // publish buf[cur]
    __builtin_amdgcn_sched_barrier(0);
    if (t + 1 < nt) stage(cur ^ 1, (t + 1) << 5);       // safe after barrier

    const char* pA = (const char*)&lA[cur][0];
    const char* pB = (const char*)&lB[cur][0];
    bf16x8 af[4], bfv[2];
#pragma unroll
    for (int mi = 0; mi < 4; ++mi) af[mi] = ldA(pA, mi);
    bfv[0] = ldB(pB, 0); bfv[1] = ldB(pB, 1);

    __builtin_amdgcn_s_setprio(1);
#pragma unroll
    for (int mi = 0; mi < 4; ++mi)
#pragma unroll
      for (int ni = 0; ni < 2; ++ni)
        acc[mi][ni] = __builtin_amdgcn_mfma_f32_16x16x32_bf16(af[mi], bfv[ni], acc[mi][ni], 0, 0, 0);
    __builtin_amdgcn_s_setprio(0);
  }

#pragma unroll
  for (int mi = 0; mi < 4; ++mi) {
#pragma unroll
    for (int ni = 0; ni < 2; ++ni) {
      const int col = n0 + wc * 32 + ni * 16 + lr;
      const float bv = bias[col];
      const int rg0 = m0 + wr * 64 + mi * 16 + lg * 4;
      if (col >= 2048) {
        const int colv = col - 2048;
        const int dd = colv & 63, hh = colv >> 6;
        const int bb = rg0 >> 11, t = rg0 & 2047;
        union { bf16_t h4[4]; unsigned long long u; } pk;
#pragma unroll
        for (int r = 0; r < 4; ++r) pk.h4[r] = (bf16_t)(acc[mi][ni][r] + bv);
        *reinterpret_cast<unsigned long long*>(
            vtb + (size_t)(bb * 16 + hh) * 131072 + (size_t)dd * 2048 + t) = pk.u;
      } else {
        const float sc = (col < 1024) ? C2S : 1.f;
#pragma unroll
        for (int r = 0; r < 4; ++r) {
          const float v = (acc[mi][ni][r] + bv) * sc;
          outb[(size_t)(rg0 + r) * ldo + col] = (bf16_t)v;
        }
      }
    }
  }
}

// ---------------- Flash attention, split-KV x2, no-max softmax, 8-wave blocks ----
// 2-buffer LDS (32KB -> 4 blocks/CU), depth-1, ONE barrier/iter (r20 verified).
__global__ __launch_bounds__(512) void attn_fwd(
    const bf16_t* __restrict__ qkv2,  // [4096][2048]  Q(scaled)|K
    const bf16_t* __restrict__ vT,    // [32][64][2048]
    bf16_t* __restrict__ a0, bf16_t* __restrict__ a1,  // [4096][1024] each
    float* __restrict__ lbuf) {       // [2][4096][16]
  __shared__ bf16_t lds[2][8192];     // per buf 16KB: K [64k][64d] @0, V^T @8192
  const int tid = threadIdx.x;
  const int wave = tid >> 6, lane = tid & 63;
  const int lr = lane & 15, lg = lane >> 4;
  const int id = blockIdx.x;
  const int xcd = id & 7, slot = id >> 3;
  const int bh = xcd * 4 + (slot & 3);
  const int rest = slot >> 2;
  const int qb = rest & 7, kvh = rest >> 3;
  const int b = bh >> 4, h = bh & 15;

  const int q0 = qb * 256 + wave * 32;
  const bf16_t* Qp = qkv2 + (size_t)(b * 2048 + q0) * 2048 + h * 64;
  bf16x8 qf[2][2];
#pragma unroll
  for (int hx = 0; hx < 2; ++hx) {
    qf[hx][0] = *reinterpret_cast<const bf16x8*>(Qp + (size_t)(hx * 16 + lr) * 2048 + lg * 8);
    qf[hx][1] = *reinterpret_cast<const bf16x8*>(Qp + (size_t)(hx * 16 + lr) * 2048 + 32 + lg * 8);
  }

  const int kr = tid >> 3;
  const int ks = (tid & 7) ^ swz8(kr);
  const bf16_t* Ksrc = qkv2 + (size_t)(b * 2048 + kvh * 1024 + kr) * 2048 + 1024 + h * 64 + ks * 8;
  const bf16_t* Vsrc = vT + (size_t)bh * 131072 + (size_t)kr * 2048 + kvh * 1024 + ks * 8;

  auto stage = [&](int buf, int kb) {
    char* base = (char*)&lds[buf][0] + wave * 1024;
    gload16(Ksrc + (size_t)kb * 131072, base);
    gload16(Vsrc + (size_t)kb * 64, base + 8192);
  };

  int kofs[4][2], vofs[4][2];
#pragma unroll
  for (int t = 0; t < 4; ++t) {
    const int kk = 32 * (t >> 1) + 8 * (lr >> 2) + 4 * (t & 1) + (lr & 3);
    const int sw = swz8(kk) << 4;
    kofs[t][0] = (kk << 7) + ((lg * 16) ^ sw);
    kofs[t][1] = (kk << 7) + ((64 + lg * 16) ^ sw);
  }
#pragma unroll
  for (int nc = 0; nc < 4; ++nc) {
    const int vr = nc * 16 + lr;
    const int sw = swz8(vr) << 4;
    vofs[nc][0] = 8192 + (vr << 7) + ((lg * 16) ^ sw);
    vofs[nc][1] = 8192 + (vr << 7) + ((64 + lg * 16) ^ sw);
  }

  f32x4 acc[2][4] = {};
  f32x4 accl[2] = {};
  bf16x8 ones;
#pragma unroll
  for (int j = 0; j < 8; ++j) ones[j] = (bf16_t)1.0f;

  stage(0, 0);

  for (int kb = 0; kb < 16; ++kb) {
    const int cur = kb & 1;
    asm volatile("s_waitcnt vmcnt(0)" ::: "memory");
    __builtin_amdgcn_s_barrier();
    __builtin_amdgcn_sched_barrier(0);
    if (kb + 1 < 16) stage(cur ^ 1, kb + 1);
    const char* bK = (const char*)&lds[cur][0];

    f32x4 s[2][4];
#pragma unroll
    for (int t = 0; t < 4; ++t) {
      const bf16x8 k0 = *reinterpret_cast<const bf16x8*>(bK + kofs[t][0]);
      const bf16x8 k1 = *reinterpret_cast<const bf16x8*>(bK + kofs[t][1]);
#pragma unroll
      for (int hx = 0; hx < 2; ++hx) {
        f32x4 z = {0.f, 0.f, 0.f, 0.f};
        z = __builtin_amdgcn_mfma_f32_16x16x32_bf16(k0, qf[hx][0], z, 0, 0, 0);
        s[hx][t] = __builtin_amdgcn_mfma_f32_16x16x32_bf16(k1, qf[hx][1], z, 0, 0, 0);
      }
    }

    bf16x8 pa[2][2];
#pragma unroll
    for (int hx = 0; hx < 2; ++hx) {
      float p[16];
#pragma unroll
      for (int t = 0; t < 4; ++t)
#pragma unroll
        for (int r = 0; r < 4; ++r)
          p[t * 4 + r] = __builtin_amdgcn_exp2f(s[hx][t][r]);
#pragma unroll
      for (int j = 0; j < 8; ++j) { pa[hx][0][j] = (bf16_t)p[j]; pa[hx][1][j] = (bf16_t)p[8 + j]; }
    }

    __builtin_amdgcn_s_setprio(1);
#pragma unroll
    for (int hx = 0; hx < 2; ++hx) {
      accl[hx] = __builtin_amdgcn_mfma_f32_16x16x32_bf16(pa[hx][0], ones, accl[hx], 0, 0, 0);
      accl[hx] = __builtin_amdgcn_mfma_f32_16x16x32_bf16(pa[hx][1], ones, accl[hx], 0, 0, 0);
    }
#pragma unroll
    for (int nc = 0; nc < 4; ++nc) {
      const bf16x8 v0 = *reinterpret_cast<const bf16x8*>(bK + vofs[nc][0]);
      const bf16x8 v1 = *reinterpret_cast<const bf16x8*>(bK + vofs[nc][1]);
#pragma unroll
      for (int hx = 0; hx < 2; ++hx) {
        acc[hx][nc] = __builtin_amdgcn_mfma_f32_16x16x32_bf16(pa[hx][0], v0, acc[hx][nc], 0, 0, 0);
        acc[hx][nc] = __builtin_amdgcn_mfma_f32_16x16x32_bf16(pa[hx][1], v1, acc[hx][nc], 0, 0, 0);
      }
    }
    __builtin_amdgcn_s_setprio(0);
  }

  bf16_t* ap = kvh ? a1 : a0;
#pragma unroll
  for (int hx = 0; hx < 2; ++hx) {
#pragma unroll
    for (int r = 0; r < 4; ++r) {
      const float lf = 1.f / accl[hx][r];
      const int qg = q0 + hx * 16 + lg * 4 + r;
      bf16_t* op = ap + (size_t)(b * 2048 + qg) * 1024 + h * 64 + lr;
#pragma unroll
      for (int nc = 0; nc < 4; ++nc) op[nc * 16] = (bf16_t)(acc[hx][nc][r] * lf);
      if (lr == 0)
        lbuf[(size_t)(kvh * 4096 + b * 2048 + qg) * 16 + h] = accl[hx][r];
    }
  }
}

// ---------------- gemm2m: out = merge(a0,a1;lbuf) @ woutT^T + bias (f32) ----------------
// 64x128 tile, 512 threads = 8 waves (2x4). Single barrier/iter (same proof as
// gemm8/attn: buf (t+1)&1 last read at iter t-1; all waves past barrier(t)
// finished those reads). lgkmcnt(0) before barrier publishes this wave's
// ds_writes. Threads <256 do the A-merge; all 512 reg-stage B. LDS 24KB.
__global__ __launch_bounds__(512) void gemm2m(
    const bf16_t* __restrict__ a0, const bf16_t* __restrict__ a1,
    const float* __restrict__ lbuf, const bf16_t* __restrict__ Bt,
    const float* __restrict__ bias, float* __restrict__ outf) {
  __shared__ bf16_t lA[2][2048];   // 64 x 32
  __shared__ bf16_t lB[2][4096];   // 128 x 32
  const int tid = threadIdx.x;
  const int wave = tid >> 6, lane = tid & 63;
  const int lr = lane & 15, lg = lane >> 4;
  const int bid = (blockIdx.x & 7) * 64 + (blockIdx.x >> 3);
  const int bm = bid >> 3, bn = bid & 7;
  const int m0 = bm * 64, n0 = bn * 128;
  const int wr = wave >> 2, wc = wave & 3;
  f32x4 acc[2][2] = {};

  const int srow = tid >> 2;
  const int scolb = ((tid & 3) << 4) ^ (((srow >> 1) & 3) << 4);
  const int scol = scolb >> 1;

  const bf16_t* pa0 = a0 + (size_t)(m0 + srow) * 1024 + scol;
  const bf16_t* pa1 = a1 + (size_t)(m0 + srow) * 1024 + scol;
  const float*  pl0 = lbuf + (size_t)(m0 + srow) * 16;
  const float*  pl1 = lbuf + (size_t)(4096 + m0 + srow) * 16;
  const bf16_t* pB0 = Bt + (size_t)(n0 + srow) * 1024 + scol;

  bf16x8 nA0 = {}, nA1 = {};
  float  nl0 = 1.f, nl1 = 1.f;
  if (tid < 256) {
    nA0 = *reinterpret_cast<const bf16x8*>(pa0);
    nA1 = *reinterpret_cast<const bf16x8*>(pa1);
    nl0 = pl0[0]; nl1 = pl1[0];
  }
  bf16x8 nB0v = *reinterpret_cast<const bf16x8*>(pB0);

  for (int t = 0; t < 32; ++t) {
    const int cur = t & 1;
    if (tid < 256) {
      const float inv = 1.f / (nl0 + nl1);
      const float w0 = nl0 * inv, w1 = nl1 * inv;
      bf16x8 mv;
#pragma unroll
      for (int j = 0; j < 8; ++j)
        mv[j] = (bf16_t)(w0 * (float)nA0[j] + w1 * (float)nA1[j]);
      *reinterpret_cast<bf16x8*>((char*)&lA[cur][0] + tid * 16) = mv;
    }
    *reinterpret_cast<bf16x8*>((char*)&lB[cur][0] + tid * 16) = nB0v;
    asm volatile("s_waitcnt lgkmcnt(0)" ::: "memory");   // own ds_writes done
    __builtin_amdgcn_s_barrier();                         // publish buf[cur]
    __builtin_amdgcn_sched_barrier(0);

    if (t < 31) {
      const int k0 = (t + 1) * 32;
      const int h = k0 >> 6;
      if (tid < 256) {
        nA0 = *reinterpret_cast<const bf16x8*>(pa0 + k0);
        nA1 = *reinterpret_cast<const bf16x8*>(pa1 + k0);
        nl0 = pl0[h]; nl1 = pl1[h];
      }
      nB0v = *reinterpret_cast<const bf16x8*>(pB0 + k0);
    }

    const char* pA = (const char*)&lA[cur][0];
    const char* pB = (const char*)&lB[cur][0];
    bf16x8 af[2], bfv[2];
#pragma unroll
    for (int mi = 0; mi < 2; ++mi) {
      const int row = wr * 32 + mi * 16 + lr;
      af[mi] = *reinterpret_cast<const bf16x8*>(pA + row * 64 + ((lg * 16) ^ (((row >> 1) & 3) << 4)));
    }
#pragma unroll
    for (int ni = 0; ni < 2; ++ni) {
      const int row = wc * 32 + ni * 16 + lr;
      bfv[ni] = *reinterpret_cast<const bf16x8*>(pB + row * 64 + ((lg * 16) ^ (((row >> 1) & 3) << 4)));
    }
    __builtin_amdgcn_s_setprio(1);
#pragma unroll
    for (int mi = 0; mi < 2; ++mi)
#pragma unroll
      for (int ni = 0; ni < 2; ++ni)
        acc[mi][ni] = __builtin_amdgcn_mfma_f32_16x16x32_bf16(af[mi], bfv[ni], acc[mi][ni], 0, 0, 0);
    __builtin_amdgcn_s_setprio(0);
  }

#pragma unroll
  for (int mi = 0; mi < 2; ++mi)
#pragma unroll
    for (int ni = 0; ni < 2; ++ni) {
      const int col = n0 + wc * 32 + ni * 16 + lr;
      const float bv = bias[col];
      const int rg0 = m0 + wr * 32 + mi * 16 + lg * 4;
#pragma unroll
      for (int r = 0; r < 4; ++r)
        outf[(size_t)(rg0 + r) * 1024 + col] = acc[mi][ni][r] + bv;
    }
}

extern "C" void kernel_launch(void* const* d_in, const int* in_sizes, int n_in,
                              void* d_out, int out_size, void* d_ws, size_t ws_size,
                              hipStream_t stream) {
  (void)in_sizes; (void)n_in; (void)out_size; (void)ws_size;
  const float* x    = (const float*)d_in[0];
  const float* Wqkv = (const float*)d_in[1];
  const float* bqkv = (const float*)d_in[2];
  const float* Wout = (const float*)d_in[3];
  const float* bout = (const float*)d_in[4];
  float* out = (float*)d_out;

  char* ws = (char*)d_ws;
  bf16_t* xb    = (bf16_t*)(ws);
  bf16_t* a0    = (bf16_t*)(ws);
  bf16_t* wqkvT = (bf16_t*)(ws + 8388608);
  bf16_t* woutT = (bf16_t*)(ws + 14680064);
  bf16_t* qkv2  = (bf16_t*)(ws + 16777216);
  bf16_t* vT    = (bf16_t*)(ws + 33554432);
  bf16_t* a1    = (bf16_t*)(ws + 41943040);
  float*  lbuf  = (float*)(ws + 50331648);

  prep<<<8192, 256, 0, stream>>>(x, Wqkv, Wout, xb, wqkvT, woutT);
  gemm8<<<768, 512, 0, stream>>>(xb, wqkvT, bqkv, qkv2, vT, 3072, 1024, 2048);
  attn_fwd<<<512, 512, 0, stream>>>(qkv2, vT, a0, a1, lbuf);
  gemm2m<<<512, 512, 0, stream>>>(a0, a1, lbuf, woutT, bout, out);
}